// Round 4
// baseline (306.373 us; speedup 1.0000x reference)
//
#include <hip/hip_runtime.h>
#include <math.h>

#define KTOP 16
#define B1   1008          // pass-1 blocks (126 per XCD)
#define T1   256           // pass-1 threads per block -> 4 waves/block
#define NC   (B1 * KTOP)   // 16128 candidates
#define T2   512           // pass-2: 8 waves, parallel candidate load, 1 barrier

typedef unsigned long long ull;

// Sortable key: larger distance first, ties -> smaller index first.
// d >= 0 so its float bits are monotone in value.
__device__ __forceinline__ ull pack_key(float d, unsigned idx) {
    return ((ull)__float_as_uint(d) << 32) | (ull)(0xFFFFFFFFu - idx);
}

// Sorted-descending bubble insert, constant indices only (SROA-safe).
__device__ __forceinline__ void insert_key(ull (&k)[KTOP], ull key) {
    ull t = key;
#pragma unroll
    for (int j = 0; j < KTOP; ++j) {
        const ull a = k[j];
        const bool c = (t > a);
        k[j] = c ? t : a;
        t    = c ? a : t;
    }
}

// 64-lane max, shuffle-only (no LDS, no barriers).
__device__ __forceinline__ ull wave_max64(ull v) {
#pragma unroll
    for (int m = 32; m >= 1; m >>= 1) {
        const ull o = __shfl_xor(v, m);
        if (o > v) v = o;
    }
    return v;
}

__device__ __forceinline__ float dist3(float x, float y, float z,
                                       float px, float py, float pz) {
#pragma clang fp contract(off)
    const float dx = x - px;
    const float dy = y - py;
    const float dz = z - pz;
    const float s  = (dx * dx + dy * dy) + dz * dz;
    return sqrtf(s);
}

// __launch_bounds__(256, 4): 4 waves/EU min -> 4 blocks/CU resident
// (16 waves/CU), VGPR cap 128. Occupancy experiment vs (512,1) which
// allowed the allocator to spend >128 VGPR and drop to 8 waves/CU.
__global__ __launch_bounds__(T1, 4) void pass1_topk(const float* __restrict__ P,
                                                    const int*   __restrict__ ipq,
                                                    int n,
                                                    ull* __restrict__ cand) {
    const int tid    = threadIdx.x;
    const int gid    = blockIdx.x * T1 + tid;
    const int stride = B1 * T1;

    const int i0 = ipq[0];
    const float pix = P[6 * i0 + 0];
    const float piy = P[6 * i0 + 1];
    const float piz = P[6 * i0 + 2];

    ull k[KTOP];
#pragma unroll
    for (int j = 0; j < KTOP; ++j) k[j] = 0ull;

    const float4* __restrict__ P4 = (const float4*)P;
    const int nPairs = n >> 1;

    // Streaming phase: 2 points (48 B) per iter, regular cached loads.
    for (int pp = gid; pp < nPairs; pp += stride) {
        const float4 q0 = P4[3 * pp + 0];
        const float4 q1 = P4[3 * pp + 1];
        const float4 q2 = P4[3 * pp + 2];
        const float dA = dist3(q0.x, q0.y, q0.z, pix, piy, piz);
        const float dB = dist3(q1.z, q1.w, q2.x, pix, piy, piz);
        const ull keyA = pack_key(dA, (unsigned)(2 * pp));
        const ull keyB = pack_key(dB, (unsigned)(2 * pp + 1));
        if (keyA > k[KTOP - 1]) insert_key(k, keyA);
        if (keyB > k[KTOP - 1]) insert_key(k, keyB);
    }
    if ((n & 1) && gid == 0) {
        const int p = n - 1;
        const float d = dist3(P[6 * p], P[6 * p + 1], P[6 * p + 2], pix, piy, piz);
        const ull key = pack_key(d, (unsigned)p);
        if (key > k[KTOP - 1]) insert_key(k, key);
    }

    // ---- Block top-16 emission, hierarchical, 1 barrier total ----
    // Stage A: per-wave 16-round pop-max over 64 sorted per-lane lists.
    __shared__ ull s_wave[(T1 / 64) * KTOP];   // 4 waves x 16 keys = 64 keys
    const int lane = tid & 63;
    const int wid  = tid >> 6;

    for (int r = 0; r < KTOP; ++r) {
        const ull c  = k[0];
        const ull rv = wave_max64(c);
        if (lane == 0) s_wave[wid * KTOP + r] = rv;
        if (c == rv) {               // keys unique -> exactly one owner pops
#pragma unroll
            for (int j = 0; j < KTOP - 1; ++j) k[j] = k[j + 1];
            k[KTOP - 1] = 0ull;
        }
    }
    __syncthreads();

    // Stage B: wave 0 merges the 64 staged keys (exactly 1 per lane).
    if (wid == 0) {
        ull a = s_wave[lane];
        for (int r = 0; r < KTOP; ++r) {
            const ull rv = wave_max64(a);
            if (lane == 0) cand[blockIdx.x * KTOP + r] = rv;
            if (a == rv) a = 0ull;
        }
    }
}

__global__ __launch_bounds__(T2, 1) void pass2_final(const float* __restrict__ P,
                                                     const int*   __restrict__ ipq,
                                                     const float* __restrict__ W,
                                                     const float* __restrict__ bvec,
                                                     const ull*   __restrict__ cand,
                                                     float* __restrict__ out) {
    const int tid  = threadIdx.x;
    const int lane = tid & 63;
    const int wid  = tid >> 6;

    // Phase 1: issue ALL candidate loads upfront (independent, latency hidden
    // by parallelism across 512 threads), THEN insert. 32 loads/thread.
    ull v[32];
#pragma unroll
    for (int j = 0; j < 32; ++j) {
        const int s = tid + j * T2;
        v[j] = (s < NC) ? cand[s] : 0ull;
    }

    ull k[KTOP];
#pragma unroll
    for (int j = 0; j < KTOP; ++j) k[j] = 0ull;
#pragma unroll
    for (int j = 0; j < 32; ++j)
        if (v[j] > k[KTOP - 1]) insert_key(k, v[j]);

    // Stage A: per-wave 16-round shuffle pop-max -> 8 sorted 16-lists.
    __shared__ ull s_wave[(T2 / 64) * KTOP];   // 1 KiB
    for (int r = 0; r < KTOP; ++r) {
        const ull c  = k[0];
        const ull rv = wave_max64(c);
        if (lane == 0) s_wave[wid * KTOP + r] = rv;
        if (c == rv) {               // unique keys -> exactly one owner pops
#pragma unroll
            for (int j = 0; j < KTOP - 1; ++j) k[j] = k[j + 1];
            k[KTOP - 1] = 0ull;
        }
    }
    __syncthreads();

    // Stage B: wave 0 merges 128 keys (2/lane); lane r keeps result r.
    if (wid == 0) {
        ull a = s_wave[lane];
        ull b = s_wave[64 + lane];
        if (b > a) { const ull t = a; a = b; b = t; }   // a >= b
        ull mine = 0ull;
        for (int r = 0; r < KTOP; ++r) {
            const ull rv = wave_max64(a);
            if (lane == r) mine = rv;
            if (a == rv) { a = b; b = 0ull; }
        }

        // Epilogue: lanes 0..15 build feat, apply W,b, write [nloc | R].
        if (lane < KTOP) {
            const ull kk = mine;
            const float d = __uint_as_float((unsigned)(kk >> 32));
            const unsigned idx = 0xFFFFFFFFu - (unsigned)(kk & 0xFFFFFFFFull);
            const int   i0  = ipq[0];
            const float pix = P[6 * i0 + 0], piy = P[6 * i0 + 1], piz = P[6 * i0 + 2];
            const float nx  = P[6 * (size_t)idx + 0];
            const float ny  = P[6 * (size_t)idx + 1];
            const float nz  = P[6 * (size_t)idx + 2];
            float dx, dy, dz;
            {
#pragma clang fp contract(off)
                dx = pix - nx; dy = piy - ny; dz = piz - nz;
            }
            const float feat[10] = { pix, piy, piz, nx, ny, nz, dx, dy, dz, d };
            float R[3];
#pragma unroll
            for (int r = 0; r < 3; ++r) {
                float acc = bvec[r];
#pragma unroll
                for (int c = 0; c < 10; ++c) acc += feat[c] * W[r * 10 + c];
                R[r] = acc;
            }
            out[6 * lane + 0] = nx;   out[6 * lane + 1] = ny;   out[6 * lane + 2] = nz;
            out[6 * lane + 3] = R[0]; out[6 * lane + 4] = R[1]; out[6 * lane + 5] = R[2];
        }
    }
}

extern "C" void kernel_launch(void* const* d_in, const int* in_sizes, int n_in,
                              void* d_out, int out_size, void* d_ws, size_t ws_size,
                              hipStream_t stream) {
    const float* P    = (const float*)d_in[0];
    const float* W    = (const float*)d_in[1];
    const float* bvec = (const float*)d_in[2];
    const int*   ipq  = (const int*)d_in[3];
    float*       out  = (float*)d_out;

    const int n = in_sizes[0] / 6;
    ull* cand = (ull*)d_ws;

    pass1_topk<<<B1, T1, 0, stream>>>(P, ipq, n, cand);
    pass2_final<<<1, T2, 0, stream>>>(P, ipq, W, bvec, cand, out);
}

// Round 6
// 293.690 us; speedup vs baseline: 1.0432x; 1.0432x over previous
//
#include <hip/hip_runtime.h>
#include <math.h>

#define KTOP 16
#define B1   504           // pass-1 blocks (63 per XCD)
#define T1   512           // pass-1 threads per block
#define NC   (B1 * KTOP)   // 8064 candidates
#define T2   512           // pass-2: 8 waves, parallel candidate load, 1 barrier

typedef unsigned long long ull;
typedef float f32x4 __attribute__((ext_vector_type(4)));

// Sortable key: larger distance first, ties -> smaller index first.
// d >= 0 so its float bits are monotone in value.
__device__ __forceinline__ ull pack_key(float d, unsigned idx) {
    return ((ull)__float_as_uint(d) << 32) | (ull)(0xFFFFFFFFu - idx);
}

// Sorted-descending bubble insert, constant indices only (SROA-safe).
__device__ __forceinline__ void insert_key(ull (&k)[KTOP], ull key) {
    ull t = key;
#pragma unroll
    for (int j = 0; j < KTOP; ++j) {
        const ull a = k[j];
        const bool c = (t > a);
        k[j] = c ? t : a;
        t    = c ? a : t;
    }
}

// 64-lane max, shuffle-only (no LDS, no barriers).
__device__ __forceinline__ ull wave_max64(ull v) {
#pragma unroll
    for (int m = 32; m >= 1; m >>= 1) {
        const ull o = __shfl_xor(v, m);
        if (o > v) v = o;
    }
    return v;
}

__device__ __forceinline__ float dist3(float x, float y, float z,
                                       float px, float py, float pz) {
#pragma clang fp contract(off)
    const float dx = x - px;
    const float dy = y - py;
    const float dz = z - pz;
    const float s  = (dx * dx + dy * dy) + dz * dz;
    return sqrtf(s);
}

__global__ __launch_bounds__(T1, 1) void pass1_topk(const float* __restrict__ P,
                                                    const int*   __restrict__ ipq,
                                                    int n,
                                                    ull* __restrict__ cand) {
    const int tid    = threadIdx.x;
    const int gid    = blockIdx.x * T1 + tid;
    const int stride = B1 * T1;

    const int i0 = ipq[0];
    const float pix = P[6 * i0 + 0];
    const float piy = P[6 * i0 + 1];
    const float piz = P[6 * i0 + 2];

    ull k[KTOP];
#pragma unroll
    for (int j = 0; j < KTOP; ++j) k[j] = 0ull;

    const f32x4* __restrict__ P4 = (const f32x4*)P;
    const int nPairs = n >> 1;

    // Streaming phase: 2 points (48 B) per iter.
    // NT (no-allocate) loads: the per-iteration 768 MB poison fill leaves the
    // whole 256 MB L3 dirty; allocating reads would force ~250 MB of dirty
    // writeback to HBM concurrent with our 192 MB read stream. NT reads leave
    // those lines in place (next fill overwrites them in-cache, no writeback).
    // (Round1-vs-2 controlled A/B: NT was 6 us faster with identical pass2.)
    for (int pp = gid; pp < nPairs; pp += stride) {
        const f32x4 q0 = __builtin_nontemporal_load(&P4[3 * pp + 0]);
        const f32x4 q1 = __builtin_nontemporal_load(&P4[3 * pp + 1]);
        const f32x4 q2 = __builtin_nontemporal_load(&P4[3 * pp + 2]);
        const float dA = dist3(q0.x, q0.y, q0.z, pix, piy, piz);
        const float dB = dist3(q1.z, q1.w, q2.x, pix, piy, piz);
        const ull keyA = pack_key(dA, (unsigned)(2 * pp));
        const ull keyB = pack_key(dB, (unsigned)(2 * pp + 1));
        if (keyA > k[KTOP - 1]) insert_key(k, keyA);
        if (keyB > k[KTOP - 1]) insert_key(k, keyB);
    }
    if ((n & 1) && gid == 0) {
        const int p = n - 1;
        const float d = dist3(P[6 * p], P[6 * p + 1], P[6 * p + 2], pix, piy, piz);
        const ull key = pack_key(d, (unsigned)p);
        if (key > k[KTOP - 1]) insert_key(k, key);
    }

    // ---- Block top-16 emission, hierarchical, 1 barrier total ----
    // Stage A: per-wave 16-round pop-max over 64 sorted per-lane lists.
    __shared__ ull s_wave[(T1 / 64) * KTOP];   // 8 waves x 16 keys = 1 KiB
    const int lane = tid & 63;
    const int wid  = tid >> 6;

    for (int r = 0; r < KTOP; ++r) {
        const ull c  = k[0];
        const ull rv = wave_max64(c);
        if (lane == 0) s_wave[wid * KTOP + r] = rv;
        if (c == rv) {               // keys unique -> exactly one owner pops
#pragma unroll
            for (int j = 0; j < KTOP - 1; ++j) k[j] = k[j + 1];
            k[KTOP - 1] = 0ull;
        }
    }
    __syncthreads();

    // Stage B: wave 0 merges the 8 sorted 16-lists (128 keys, 2 per lane).
    if (wid == 0) {
        ull a = s_wave[lane];
        ull b = s_wave[64 + lane];
        if (b > a) { const ull t = a; a = b; b = t; }   // local sort: a >= b
        for (int r = 0; r < KTOP; ++r) {
            const ull rv = wave_max64(a);
            if (lane == 0) cand[blockIdx.x * KTOP + r] = rv;
            if (a == rv) { a = b; b = 0ull; }
        }
    }
}

__global__ __launch_bounds__(T2, 1) void pass2_final(const float* __restrict__ P,
                                                     const int*   __restrict__ ipq,
                                                     const float* __restrict__ W,
                                                     const float* __restrict__ bvec,
                                                     const ull*   __restrict__ cand,
                                                     float* __restrict__ out) {
    const int tid  = threadIdx.x;
    const int lane = tid & 63;
    const int wid  = tid >> 6;

    // Phase 1: issue ALL candidate loads upfront (independent, latency hidden
    // by parallelism across 512 threads), THEN insert. 16 loads/thread.
    ull v[16];
#pragma unroll
    for (int j = 0; j < 16; ++j) {
        const int s = tid + j * T2;
        v[j] = (s < NC) ? cand[s] : 0ull;
    }

    ull k[KTOP];
#pragma unroll
    for (int j = 0; j < KTOP; ++j) k[j] = 0ull;
#pragma unroll
    for (int j = 0; j < 16; ++j)
        if (v[j] > k[KTOP - 1]) insert_key(k, v[j]);

    // Stage A: per-wave 16-round shuffle pop-max -> 8 sorted 16-lists.
    __shared__ ull s_wave[(T2 / 64) * KTOP];   // 1 KiB
    for (int r = 0; r < KTOP; ++r) {
        const ull c  = k[0];
        const ull rv = wave_max64(c);
        if (lane == 0) s_wave[wid * KTOP + r] = rv;
        if (c == rv) {               // unique keys -> exactly one owner pops
#pragma unroll
            for (int j = 0; j < KTOP - 1; ++j) k[j] = k[j + 1];
            k[KTOP - 1] = 0ull;
        }
    }
    __syncthreads();

    // Stage B: wave 0 merges 128 keys (2/lane); lane r keeps result r.
    if (wid == 0) {
        ull a = s_wave[lane];
        ull b = s_wave[64 + lane];
        if (b > a) { const ull t = a; a = b; b = t; }   // a >= b
        ull mine = 0ull;
        for (int r = 0; r < KTOP; ++r) {
            const ull rv = wave_max64(a);
            if (lane == r) mine = rv;
            if (a == rv) { a = b; b = 0ull; }
        }

        // Epilogue: lanes 0..15 build feat, apply W,b, write [nloc | R].
        if (lane < KTOP) {
            const ull kk = mine;
            const float d = __uint_as_float((unsigned)(kk >> 32));
            const unsigned idx = 0xFFFFFFFFu - (unsigned)(kk & 0xFFFFFFFFull);
            const int   i0  = ipq[0];
            const float pix = P[6 * i0 + 0], piy = P[6 * i0 + 1], piz = P[6 * i0 + 2];
            const float nx  = P[6 * (size_t)idx + 0];
            const float ny  = P[6 * (size_t)idx + 1];
            const float nz  = P[6 * (size_t)idx + 2];
            float dx, dy, dz;
            {
#pragma clang fp contract(off)
                dx = pix - nx; dy = piy - ny; dz = piz - nz;
            }
            const float feat[10] = { pix, piy, piz, nx, ny, nz, dx, dy, dz, d };
            float R[3];
#pragma unroll
            for (int r = 0; r < 3; ++r) {
                float acc = bvec[r];
#pragma unroll
                for (int c = 0; c < 10; ++c) acc += feat[c] * W[r * 10 + c];
                R[r] = acc;
            }
            out[6 * lane + 0] = nx;   out[6 * lane + 1] = ny;   out[6 * lane + 2] = nz;
            out[6 * lane + 3] = R[0]; out[6 * lane + 4] = R[1]; out[6 * lane + 5] = R[2];
        }
    }
}

extern "C" void kernel_launch(void* const* d_in, const int* in_sizes, int n_in,
                              void* d_out, int out_size, void* d_ws, size_t ws_size,
                              hipStream_t stream) {
    const float* P    = (const float*)d_in[0];
    const float* W    = (const float*)d_in[1];
    const float* bvec = (const float*)d_in[2];
    const int*   ipq  = (const int*)d_in[3];
    float*       out  = (float*)d_out;

    const int n = in_sizes[0] / 6;
    ull* cand = (ull*)d_ws;

    pass1_topk<<<B1, T1, 0, stream>>>(P, ipq, n, cand);
    pass2_final<<<1, T2, 0, stream>>>(P, ipq, W, bvec, cand, out);
}